// Round 3
// baseline (1180.261 us; speedup 1.0000x reference)
//
#include <hip/hip_runtime.h>
#include <math.h>
#include <limits.h>

#define QN 1024
#define NN 50000
#define NPAD 50048
#define DD 512
#define KNN 10
#define NT 128            /* data points per block  */
#define QTB 128           /* queries per block      */
#define BK 32             /* k-chunk                */
#define NS 391            /* ceil(50000/128)        */
#define QB 8              /* 1024/128               */

/* workspace layout, in 4-byte elements */
#define WS_D2 0
#define WS_CD NPAD
#define WS_CI (WS_CD + QN * NS * KNN)

typedef __attribute__((ext_vector_type(8))) short short8;  /* 8 bf16 = 4 VGPR */
typedef __attribute__((ext_vector_type(4))) float f32x4;

#define PANEL_B 1152      /* 64 chunks * 16B + 8 * 16B pad; 288 words = 9*32 */
#define REGION_B (8 * PANEL_B)

__device__ __forceinline__ bool lless(float d1, int i1, float d2, int i2) {
  return (d1 < d2) || (d1 == d2 && i1 < i2);
}

/* split 2 floats into packed bf16 hi-pair and lo-pair words (RNE) */
__device__ __forceinline__ void cvt2(float x, float y, unsigned& hi, unsigned& lo) {
  unsigned ux = __float_as_uint(x), uy = __float_as_uint(y);
  unsigned rx = ux + 0x7fffu + ((ux >> 16) & 1u);
  unsigned ry = uy + 0x7fffu + ((uy >> 16) & 1u);
  hi = (rx >> 16) | (ry & 0xffff0000u);
  float xl = x - __uint_as_float(rx & 0xffff0000u);
  float yl = y - __uint_as_float(ry & 0xffff0000u);
  unsigned uxl = __float_as_uint(xl), uyl = __float_as_uint(yl);
  unsigned rxl = uxl + 0x7fffu + ((uxl >> 16) & 1u);
  unsigned ryl = uyl + 0x7fffu + ((uyl >> 16) & 1u);
  lo = (rxl >> 16) | (ryl & 0xffff0000u);
}

/* ---------------- K1: data row norms (padded with +inf) ---------------- */
__global__ __launch_bounds__(256) void norms_kernel(
    const float* __restrict__ dat, float* __restrict__ ws) {
  int w = threadIdx.x >> 6, lane = threadIdx.x & 63;
  int row = blockIdx.x * 4 + w;
  if (row >= NPAD) return;
  if (row >= NN) {
    if (lane == 0) ws[WS_D2 + row] = __builtin_inff();
    return;
  }
  const float4* p = (const float4*)(dat + (size_t)row * DD);
  float s = 0.f;
#pragma unroll
  for (int i = 0; i < 2; i++) {
    float4 v = p[lane + i * 64];
    s = fmaf(v.x, v.x, s); s = fmaf(v.y, v.y, s);
    s = fmaf(v.z, v.z, s); s = fmaf(v.w, v.w, s);
  }
#pragma unroll
  for (int off = 32; off; off >>= 1) s += __shfl_down(s, off, 64);
  if (lane == 0) ws[WS_D2 + row] = s;
}

/* ---------------- K2: split-bf16 MFMA GEMM + fused per-slice top-10 ----- */
struct EpiT {
  float sq[32][132];
  float md[32][8][KNN];
  int   mi[32][8][KNN];
};
union SmemU {
  unsigned char stage[4 * REGION_B];  /* AH | AL | BH | BL */
  EpiT e;
};

__global__ __launch_bounds__(256, 2) void knn_chunk(
    const float* __restrict__ Xm, const float* __restrict__ dat,
    float* __restrict__ ws) {
  __shared__ __align__(16) SmemU sm;
  const int qbase = blockIdx.x * QTB;
  const int nbase = blockIdx.y * NT;
  const int t = threadIdx.x;
  const int lane = t & 63, wave = t >> 6;
  const int wn = wave & 1, wq = wave >> 1;

  f32x4 acc[4][4];
#pragma unroll
  for (int i = 0; i < 4; i++)
#pragma unroll
    for (int j = 0; j < 4; j++) acc[i][j] = (f32x4)0.f;

  /* lane-linear fragment offset within a panel (16B pad every 8 chunks) */
  const int fragoff = lane * 16 + ((lane >> 3) << 4);

  for (int kk = 0; kk < DD; kk += BK) {
    __syncthreads();
#pragma unroll
    for (int it = 0; it < 2; it++) {   /* 512 8-k chunk positions per side */
      int cp = t + it * 256;
      int row = cp >> 2, quad = cp & 3;
      int c = (quad << 4) | (row & 15);
      int off = (row >> 4) * PANEL_B + c * 16 + ((c >> 3) << 4);
      { /* A side: X queries */
        const float* src = Xm + (size_t)(qbase + row) * DD + kk + quad * 8;
        float4 v0 = *(const float4*)src;
        float4 v1 = *(const float4*)(src + 4);
        unsigned h0, h1, h2, h3, l0, l1, l2, l3;
        cvt2(v0.x, v0.y, h0, l0); cvt2(v0.z, v0.w, h1, l1);
        cvt2(v1.x, v1.y, h2, l2); cvt2(v1.z, v1.w, h3, l3);
        *(uint4*)(sm.stage + off)            = make_uint4(h0, h1, h2, h3);
        *(uint4*)(sm.stage + REGION_B + off) = make_uint4(l0, l1, l2, l3);
      }
      { /* B side: data points (zero-pad OOB rows) */
        int gr = nbase + row;
        float4 v0 = make_float4(0.f, 0.f, 0.f, 0.f), v1 = v0;
        if (gr < NN) {
          const float* src = dat + (size_t)gr * DD + kk + quad * 8;
          v0 = *(const float4*)src; v1 = *(const float4*)(src + 4);
        }
        unsigned h0, h1, h2, h3, l0, l1, l2, l3;
        cvt2(v0.x, v0.y, h0, l0); cvt2(v0.z, v0.w, h1, l1);
        cvt2(v1.x, v1.y, h2, l2); cvt2(v1.z, v1.w, h3, l3);
        *(uint4*)(sm.stage + 2 * REGION_B + off) = make_uint4(h0, h1, h2, h3);
        *(uint4*)(sm.stage + 3 * REGION_B + off) = make_uint4(l0, l1, l2, l3);
      }
    }
    __syncthreads();

    short8 ah[4], al_[4], bh[4], bl_[4];
#pragma unroll
    for (int i = 0; i < 4; i++) {
      ah[i]  = *(const short8*)(sm.stage + (wq * 4 + i) * PANEL_B + fragoff);
      al_[i] = *(const short8*)(sm.stage + REGION_B + (wq * 4 + i) * PANEL_B + fragoff);
      bh[i]  = *(const short8*)(sm.stage + 2 * REGION_B + (wn * 4 + i) * PANEL_B + fragoff);
      bl_[i] = *(const short8*)(sm.stage + 3 * REGION_B + (wn * 4 + i) * PANEL_B + fragoff);
    }
#pragma unroll
    for (int mt = 0; mt < 4; mt++)
#pragma unroll
      for (int nt = 0; nt < 4; nt++) {
        acc[mt][nt] = __builtin_amdgcn_mfma_f32_16x16x32_bf16(ah[mt],  bh[nt],  acc[mt][nt], 0, 0, 0);
        acc[mt][nt] = __builtin_amdgcn_mfma_f32_16x16x32_bf16(ah[mt],  bl_[nt], acc[mt][nt], 0, 0, 0);
        acc[mt][nt] = __builtin_amdgcn_mfma_f32_16x16x32_bf16(al_[mt], bh[nt],  acc[mt][nt], 0, 0, 0);
      }
  }

  /* ---- epilogue: key = d2 - 2*dot (x2 constant per query), top-10/slice.
     NOTE: p-loop MUST be fully unrolled so acc[] indices are compile-time
     constants; a runtime index demotes acc to scratch (R2: 3.4 GB spill). */
  const float INF = __builtin_inff();
#pragma unroll
  for (int p = 0; p < 4; p++) {
    __syncthreads();
    if (wq == (p >> 1)) {
#pragma unroll
      for (int tt = 0; tt < 2; tt++) {
        const int tq = (p & 1) * 2 + tt;
#pragma unroll
        for (int nt = 0; nt < 4; nt++) {
          int nl = wn * 64 + nt * 16 + (lane & 15);
          float d2v = ws[WS_D2 + nbase + nl];
#pragma unroll
          for (int rg = 0; rg < 4; rg++) {
            int qp = tt * 16 + (lane >> 4) * 4 + rg;
            sm.e.sq[qp][nl] = fmaf(-2.f, acc[tq][nt][rg], d2v);
          }
        }
      }
    }
    __syncthreads();
    {
      int r = t >> 3, mm = t & 7;
      float td[KNN]; int ti[KNN];
#pragma unroll
      for (int u = 0; u < KNN; u++) { td[u] = INF; ti[u] = INT_MAX; }
      for (int it = 0; it < 16; it++) {
        int cc = it * 8 + mm;              /* stride-8 scan: <=2-way banks */
        float v = sm.e.sq[r][cc];
        int idx = nbase + cc;
        if (lless(v, idx, td[KNN - 1], ti[KNN - 1])) {
          float cd = v; int cidx = idx;
#pragma unroll
          for (int u = 0; u < KNN; u++) {
            if (lless(cd, cidx, td[u], ti[u])) {
              float tmpd = td[u]; td[u] = cd; cd = tmpd;
              int tmpi = ti[u]; ti[u] = cidx; cidx = tmpi;
            }
          }
        }
      }
#pragma unroll
      for (int u = 0; u < KNN; u++) { sm.e.md[r][mm][u] = td[u]; sm.e.mi[r][mm][u] = ti[u]; }
    }
    __syncthreads();
    if ((t & 7) == 0) {                    /* stable 8-way merge, 1 thr/row */
      int r = t >> 3;
      int qg = qbase + p * 32 + r;
      float* outd = ws + WS_CD + ((size_t)qg * NS + blockIdx.y) * KNN;
      int*   outi = ((int*)ws) + WS_CI + ((size_t)qg * NS + blockIdx.y) * KNN;
      int hp[8] = {0, 0, 0, 0, 0, 0, 0, 0};
      for (int pick = 0; pick < KNN; pick++) {
        float bd = 0.f; int bi = 0; int bm = -1;
        for (int m2 = 0; m2 < 8; m2++) {
          if (hp[m2] >= KNN) continue;
          float hd = sm.e.md[r][m2][hp[m2]];
          int   hi = sm.e.mi[r][m2][hp[m2]];
          if (bm < 0 || lless(hd, hi, bd, bi)) { bd = hd; bi = hi; bm = m2; }
        }
        outd[pick] = bd; outi[pick] = bi; hp[bm]++;
      }
    }
  }
}

/* ---------------- K3: per-query final merge + mode ---------------- */
__global__ __launch_bounds__(64) void knn_final(
    const int* __restrict__ targets, float* __restrict__ ws,
    float* __restrict__ out) {
  const int q = blockIdx.x;
  const int t = threadIdx.x;
  const float INF = __builtin_inff();
  const float* cd = ws + WS_CD + (size_t)q * NS * KNN;
  const int*   ci = ((const int*)ws) + WS_CI + (size_t)q * NS * KNN;
  const int NC = NS * KNN;

  float td[KNN]; int ti[KNN];
#pragma unroll
  for (int u = 0; u < KNN; u++) { td[u] = INF; ti[u] = INT_MAX; }
  for (int j = t; j < NC; j += 64) {
    float d = cd[j]; int i = ci[j];
    if (lless(d, i, td[KNN - 1], ti[KNN - 1])) {
      float c0 = d; int c1 = i;
#pragma unroll
      for (int u = 0; u < KNN; u++) {
        if (lless(c0, c1, td[u], ti[u])) {
          float tmpd = td[u]; td[u] = c0; c0 = tmpd;
          int tmpi = ti[u]; ti[u] = c1; c1 = tmpi;
        }
      }
    }
  }

  __shared__ float wd[64][KNN]; __shared__ int wi[64][KNN];
  __shared__ float m2d[8][KNN]; __shared__ int m2i[8][KNN];
#pragma unroll
  for (int u = 0; u < KNN; u++) { wd[t][u] = td[u]; wi[t][u] = ti[u]; }
  __syncthreads();
  if (t < 8) {
    int hp[8] = {0, 0, 0, 0, 0, 0, 0, 0};
    for (int pick = 0; pick < KNN; pick++) {
      float bd = 0.f; int bi = 0; int bm = -1;
      for (int mm = 0; mm < 8; mm++) {
        if (hp[mm] >= KNN) continue;
        int lid = t * 8 + mm;
        float hd = wd[lid][hp[mm]]; int hi = wi[lid][hp[mm]];
        if (bm < 0 || lless(hd, hi, bd, bi)) { bd = hd; bi = hi; bm = mm; }
      }
      m2d[t][pick] = bd; m2i[t][pick] = bi; hp[bm]++;
    }
  }
  __syncthreads();
  if (t == 0) {
    int hp[8] = {0, 0, 0, 0, 0, 0, 0, 0};
    int fi[KNN];
    for (int pick = 0; pick < KNN; pick++) {
      float bd = 0.f; int bi = 0; int bm = -1;
      for (int mm = 0; mm < 8; mm++) {
        if (hp[mm] >= KNN) continue;
        float hd = m2d[mm][hp[mm]]; int hi = m2i[mm][hp[mm]];
        if (bm < 0 || lless(hd, hi, bd, bi)) { bd = hd; bi = hi; bm = mm; }
      }
      fi[pick] = bi; hp[bm]++;
    }
    int lab[KNN];
#pragma unroll
    for (int u = 0; u < KNN; u++) lab[u] = targets[fi[u]];
    int bc = 0, bl = INT_MAX;
#pragma unroll
    for (int i = 0; i < KNN; i++) {
      int c = 0;
#pragma unroll
      for (int j = 0; j < KNN; j++) c += (lab[j] == lab[i]) ? 1 : 0;
      if (c > bc || (c == bc && lab[i] < bl)) { bc = c; bl = lab[i]; }
    }
    out[q] = (float)bl;
  }
}

extern "C" void kernel_launch(void* const* d_in, const int* in_sizes, int n_in,
                              void* d_out, int out_size, void* d_ws, size_t ws_size,
                              hipStream_t stream) {
  const float* Xm  = (const float*)d_in[0];
  const float* dat = (const float*)d_in[1];
  const int* targets = (const int*)d_in[2];
  float* out = (float*)d_out;
  float* ws  = (float*)d_ws;

  hipLaunchKernelGGL(norms_kernel, dim3(NPAD / 4), dim3(256), 0, stream, dat, ws);
  hipLaunchKernelGGL(knn_chunk, dim3(QB, NS), dim3(256), 0, stream, Xm, dat, ws);
  hipLaunchKernelGGL(knn_final, dim3(QN), dim3(64), 0, stream, targets, ws, out);
}

// Round 4
// 652.733 us; speedup vs baseline: 1.8082x; 1.8082x over previous
//
#include <hip/hip_runtime.h>
#include <math.h>
#include <limits.h>

#define QN 1024
#define NN 50000
#define NPAD 50048
#define DD 512
#define KNN 10
#define NT 128            /* data points per block  */
#define QTB 128           /* queries per block      */
#define BK 32             /* k-chunk                */
#define NS 391            /* ceil(50000/128)        */
#define QB 8              /* 1024/128               */

/* workspace layout, in 4-byte words */
#define WS_D2 0
#define WS_XH NPAD                         /* X hi, bf16 row-major: 1024*512*2B */
#define WS_XL (WS_XH + QN * DD / 2)
#define WS_CD (WS_XL + QN * DD / 2)
#define WS_CI (WS_CD + QN * NS * KNN)      /* total ~34.3 MB */

typedef __attribute__((ext_vector_type(8))) short short8;  /* 8 bf16 = 4 VGPR */
typedef __attribute__((ext_vector_type(4))) float f32x4;

__device__ __forceinline__ bool lless(float d1, int i1, float d2, int i2) {
  return (d1 < d2) || (d1 == d2 && i1 < i2);
}

/* split 2 floats into packed bf16 hi-pair and lo-pair words (RNE) */
__device__ __forceinline__ void cvt2(float x, float y, unsigned& hi, unsigned& lo) {
  unsigned ux = __float_as_uint(x), uy = __float_as_uint(y);
  unsigned rx = ux + 0x7fffu + ((ux >> 16) & 1u);
  unsigned ry = uy + 0x7fffu + ((uy >> 16) & 1u);
  hi = (rx >> 16) | (ry & 0xffff0000u);
  float xl = x - __uint_as_float(rx & 0xffff0000u);
  float yl = y - __uint_as_float(ry & 0xffff0000u);
  unsigned uxl = __float_as_uint(xl), uyl = __float_as_uint(yl);
  unsigned rxl = uxl + 0x7fffu + ((uxl >> 16) & 1u);
  unsigned ryl = uyl + 0x7fffu + ((uyl >> 16) & 1u);
  lo = (rxl >> 16) | (ryl & 0xffff0000u);
}

__device__ __forceinline__ void glds16(const void* g, void* l) {
  __builtin_amdgcn_global_load_lds(
      (const __attribute__((address_space(1))) unsigned*)g,
      (__attribute__((address_space(3))) unsigned*)l, 16, 0, 0);
}

/* ---------------- K0: preconvert X to split-bf16 row-major -------------- */
__global__ __launch_bounds__(256) void convx_kernel(
    const float* __restrict__ Xm, float* __restrict__ ws) {
  int w = threadIdx.x >> 6, lane = threadIdx.x & 63;
  int row = blockIdx.x * 4 + w;                 /* grid = 256 -> rows 0..1023 */
  const float4* p = (const float4*)(Xm + (size_t)row * DD) + lane * 2;
  float4 v0 = p[0], v1 = p[1];
  unsigned h[4], l[4];
  cvt2(v0.x, v0.y, h[0], l[0]); cvt2(v0.z, v0.w, h[1], l[1]);
  cvt2(v1.x, v1.y, h[2], l[2]); cvt2(v1.z, v1.w, h[3], l[3]);
  ((uint4*)(ws + WS_XH))[row * 64 + lane] = make_uint4(h[0], h[1], h[2], h[3]);
  ((uint4*)(ws + WS_XL))[row * 64 + lane] = make_uint4(l[0], l[1], l[2], l[3]);
}

/* ---------------- K1: data row norms (padded with +inf) ---------------- */
__global__ __launch_bounds__(256) void norms_kernel(
    const float* __restrict__ dat, float* __restrict__ ws) {
  int w = threadIdx.x >> 6, lane = threadIdx.x & 63;
  int row = blockIdx.x * 4 + w;
  if (row >= NPAD) return;
  if (row >= NN) {
    if (lane == 0) ws[WS_D2 + row] = __builtin_inff();
    return;
  }
  const float4* p = (const float4*)(dat + (size_t)row * DD);
  float s = 0.f;
#pragma unroll
  for (int i = 0; i < 2; i++) {
    float4 v = p[lane + i * 64];
    s = fmaf(v.x, v.x, s); s = fmaf(v.y, v.y, s);
    s = fmaf(v.z, v.z, s); s = fmaf(v.w, v.w, s);
  }
#pragma unroll
  for (int off = 32; off; off >>= 1) s += __shfl_down(s, off, 64);
  if (lane == 0) ws[WS_D2 + row] = s;
}

/* ---------------- K2: split-bf16 MFMA GEMM + fused per-slice top-10 -----
   m97 structure: A staged via global_load_lds (preconverted, fragment-order
   lane-linear LDS), B converted in-registers then ds_write. 2-barrier K-loop.
*/
struct StageT {
  unsigned char ah[8192], al[8192], bh[8192], bl[8192];  /* 8 panels x 1KB */
};
struct EpiT {
  float sq[32][132];
  float md[32][8][KNN];
  int   mi[32][8][KNN];
};
union SmemU { StageT s; EpiT e; };

__global__ __launch_bounds__(256, 2) void knn_chunk(
    const float* __restrict__ dat, float* __restrict__ ws) {
  __shared__ __align__(16) SmemU sm;
  const int qbase = blockIdx.x * QTB;
  const int nbase = blockIdx.y * NT;
  const int t = threadIdx.x;
  const int lane = t & 63, wave = t >> 6;
  const int wn = wave & 1, wq = wave >> 1;
  const unsigned short* xh = (const unsigned short*)(ws + WS_XH);
  const unsigned short* xl = (const unsigned short*)(ws + WS_XL);

  f32x4 acc[4][4];
#pragma unroll
  for (int i = 0; i < 4; i++)
#pragma unroll
    for (int j = 0; j < 4; j++) acc[i][j] = (f32x4)0.f;

  /* B staging role: one thread = one row-half (16 k) */
  const int brow = t >> 1, bh_half = t & 1;
  const int bgr = nbase + brow;
  const int bpanel = (brow >> 4) * 1024;
  const int bchunk = (brow & 15) * 16;

  for (int kk = 0; kk < DD; kk += BK) {
    __syncthreads();
    /* ---- A staging: 16 panels (AH0..7, AL0..7), 4 per wave, pure DMA ---- */
#pragma unroll
    for (int i = 0; i < 4; i++) {
      int pp = wave * 4 + i;
      int p = pp & 7;
      const unsigned short* g =
          (pp < 8 ? xh : xl) +
          (size_t)(qbase + p * 16 + (lane & 15)) * DD + kk + (lane >> 4) * 8;
      unsigned char* ldst = (pp < 8 ? sm.s.ah : sm.s.al) + p * 1024;
      glds16(g, ldst);
    }
    /* ---- B staging: load 16 floats, split-convert, 4x ds_write_b128 ---- */
    {
      float4 v0 = make_float4(0.f, 0.f, 0.f, 0.f), v1 = v0, v2 = v0, v3 = v0;
      if (bgr < NN) {
        const float4* src = (const float4*)(dat + (size_t)bgr * DD + kk + bh_half * 16);
        v0 = src[0]; v1 = src[1]; v2 = src[2]; v3 = src[3];
      }
      unsigned hw[8], lw[8];
      cvt2(v0.x, v0.y, hw[0], lw[0]); cvt2(v0.z, v0.w, hw[1], lw[1]);
      cvt2(v1.x, v1.y, hw[2], lw[2]); cvt2(v1.z, v1.w, hw[3], lw[3]);
      cvt2(v2.x, v2.y, hw[4], lw[4]); cvt2(v2.z, v2.w, hw[5], lw[5]);
      cvt2(v3.x, v3.y, hw[6], lw[6]); cvt2(v3.z, v3.w, hw[7], lw[7]);
      unsigned char* bhp = sm.s.bh + bpanel;
      unsigned char* blp = sm.s.bl + bpanel;
      *(uint4*)(bhp + (2 * bh_half) * 256 + bchunk)     = make_uint4(hw[0], hw[1], hw[2], hw[3]);
      *(uint4*)(bhp + (2 * bh_half + 1) * 256 + bchunk) = make_uint4(hw[4], hw[5], hw[6], hw[7]);
      *(uint4*)(blp + (2 * bh_half) * 256 + bchunk)     = make_uint4(lw[0], lw[1], lw[2], lw[3]);
      *(uint4*)(blp + (2 * bh_half + 1) * 256 + bchunk) = make_uint4(lw[4], lw[5], lw[6], lw[7]);
    }
    __syncthreads();

    const int fragoff = lane * 16;
    short8 fah[4], fal[4], fbh[4], fbl[4];
#pragma unroll
    for (int i = 0; i < 4; i++) {
      fah[i] = *(const short8*)(sm.s.ah + (wq * 4 + i) * 1024 + fragoff);
      fal[i] = *(const short8*)(sm.s.al + (wq * 4 + i) * 1024 + fragoff);
      fbh[i] = *(const short8*)(sm.s.bh + (wn * 4 + i) * 1024 + fragoff);
      fbl[i] = *(const short8*)(sm.s.bl + (wn * 4 + i) * 1024 + fragoff);
    }
#pragma unroll
    for (int mt = 0; mt < 4; mt++)
#pragma unroll
      for (int nt = 0; nt < 4; nt++) {
        acc[mt][nt] = __builtin_amdgcn_mfma_f32_16x16x32_bf16(fah[mt], fbh[nt], acc[mt][nt], 0, 0, 0);
        acc[mt][nt] = __builtin_amdgcn_mfma_f32_16x16x32_bf16(fah[mt], fbl[nt], acc[mt][nt], 0, 0, 0);
        acc[mt][nt] = __builtin_amdgcn_mfma_f32_16x16x32_bf16(fal[mt], fbh[nt], acc[mt][nt], 0, 0, 0);
      }
  }

  /* ---- epilogue: key = d2 - 2*dot (x2 constant per query), top-10/slice.
     p-loop MUST stay fully unrolled: runtime acc[] index -> scratch demotion
     (R2: 3.4 GB spill). */
  const float INF = __builtin_inff();
#pragma unroll
  for (int p = 0; p < 4; p++) {
    __syncthreads();
    if (wq == (p >> 1)) {
#pragma unroll
      for (int tt = 0; tt < 2; tt++) {
        const int tq = (p & 1) * 2 + tt;
#pragma unroll
        for (int nt = 0; nt < 4; nt++) {
          int nl = wn * 64 + nt * 16 + (lane & 15);
          float d2v = ws[WS_D2 + nbase + nl];
#pragma unroll
          for (int rg = 0; rg < 4; rg++) {
            int qp = tt * 16 + (lane >> 4) * 4 + rg;
            sm.e.sq[qp][nl] = fmaf(-2.f, acc[tq][nt][rg], d2v);
          }
        }
      }
    }
    __syncthreads();
    {
      int r = t >> 3, mm = t & 7;
      float td[KNN]; int ti[KNN];
#pragma unroll
      for (int u = 0; u < KNN; u++) { td[u] = INF; ti[u] = INT_MAX; }
      for (int it = 0; it < 16; it++) {
        int cc = it * 8 + mm;              /* stride-8 scan: <=2-way banks */
        float v = sm.e.sq[r][cc];
        int idx = nbase + cc;
        if (lless(v, idx, td[KNN - 1], ti[KNN - 1])) {
          float cd = v; int cidx = idx;
#pragma unroll
          for (int u = 0; u < KNN; u++) {
            if (lless(cd, cidx, td[u], ti[u])) {
              float tmpd = td[u]; td[u] = cd; cd = tmpd;
              int tmpi = ti[u]; ti[u] = cidx; cidx = tmpi;
            }
          }
        }
      }
#pragma unroll
      for (int u = 0; u < KNN; u++) { sm.e.md[r][mm][u] = td[u]; sm.e.mi[r][mm][u] = ti[u]; }
    }
    __syncthreads();
    if ((t & 7) == 0) {                    /* stable 8-way merge, 1 thr/row */
      int r = t >> 3;
      int qg = qbase + p * 32 + r;
      float* outd = ws + WS_CD + ((size_t)qg * NS + blockIdx.y) * KNN;
      int*   outi = ((int*)ws) + WS_CI + ((size_t)qg * NS + blockIdx.y) * KNN;
      int hp[8] = {0, 0, 0, 0, 0, 0, 0, 0};
      for (int pick = 0; pick < KNN; pick++) {
        float bd = 0.f; int bi = 0; int bm = -1;
        for (int m2 = 0; m2 < 8; m2++) {
          if (hp[m2] >= KNN) continue;
          float hd = sm.e.md[r][m2][hp[m2]];
          int   hi = sm.e.mi[r][m2][hp[m2]];
          if (bm < 0 || lless(hd, hi, bd, bi)) { bd = hd; bi = hi; bm = m2; }
        }
        outd[pick] = bd; outi[pick] = bi; hp[bm]++;
      }
    }
  }
}

/* ---------------- K3: per-query final merge + mode (256 thr) ----------- */
__global__ __launch_bounds__(256) void knn_final(
    const int* __restrict__ targets, float* __restrict__ ws,
    float* __restrict__ out) {
  const int q = blockIdx.x;
  const int t = threadIdx.x;
  const float INF = __builtin_inff();
  const float* cd = ws + WS_CD + (size_t)q * NS * KNN;
  const int*   ci = ((const int*)ws) + WS_CI + (size_t)q * NS * KNN;
  const int NC = NS * KNN;                 /* 3910 */

  float td[KNN]; int ti[KNN];
#pragma unroll
  for (int u = 0; u < KNN; u++) { td[u] = INF; ti[u] = INT_MAX; }
  for (int j = t; j < NC; j += 256) {
    float d = cd[j]; int i = ci[j];
    if (lless(d, i, td[KNN - 1], ti[KNN - 1])) {
      float c0 = d; int c1 = i;
#pragma unroll
      for (int u = 0; u < KNN; u++) {
        if (lless(c0, c1, td[u], ti[u])) {
          float tmpd = td[u]; td[u] = c0; c0 = tmpd;
          int tmpi = ti[u]; ti[u] = c1; c1 = tmpi;
        }
      }
    }
  }

  __shared__ float wd[256][KNN]; __shared__ int wi[256][KNN];
  __shared__ float m2d[32][KNN]; __shared__ int m2i[32][KNN];
  __shared__ float m3d[4][KNN];  __shared__ int m3i[4][KNN];
#pragma unroll
  for (int u = 0; u < KNN; u++) { wd[t][u] = td[u]; wi[t][u] = ti[u]; }
  __syncthreads();
  if (t < 32) {
    int hp[8] = {0, 0, 0, 0, 0, 0, 0, 0};
    for (int pick = 0; pick < KNN; pick++) {
      float bd = 0.f; int bi = 0; int bm = -1;
      for (int mm = 0; mm < 8; mm++) {
        if (hp[mm] >= KNN) continue;
        int lid = t * 8 + mm;
        float hd = wd[lid][hp[mm]]; int hi = wi[lid][hp[mm]];
        if (bm < 0 || lless(hd, hi, bd, bi)) { bd = hd; bi = hi; bm = mm; }
      }
      m2d[t][pick] = bd; m2i[t][pick] = bi; hp[bm]++;
    }
  }
  __syncthreads();
  if (t < 4) {
    int hp[8] = {0, 0, 0, 0, 0, 0, 0, 0};
    for (int pick = 0; pick < KNN; pick++) {
      float bd = 0.f; int bi = 0; int bm = -1;
      for (int mm = 0; mm < 8; mm++) {
        if (hp[mm] >= KNN) continue;
        float hd = m2d[t * 8 + mm][hp[mm]]; int hi = m2i[t * 8 + mm][hp[mm]];
        if (bm < 0 || lless(hd, hi, bd, bi)) { bd = hd; bi = hi; bm = mm; }
      }
      m3d[t][pick] = bd; m3i[t][pick] = bi; hp[bm]++;
    }
  }
  __syncthreads();
  if (t == 0) {
    int hp[4] = {0, 0, 0, 0};
    int fi[KNN];
    for (int pick = 0; pick < KNN; pick++) {
      float bd = 0.f; int bi = 0; int bm = -1;
      for (int mm = 0; mm < 4; mm++) {
        if (hp[mm] >= KNN) continue;
        float hd = m3d[mm][hp[mm]]; int hi = m3i[mm][hp[mm]];
        if (bm < 0 || lless(hd, hi, bd, bi)) { bd = hd; bi = hi; bm = mm; }
      }
      fi[pick] = bi; hp[bm]++;
    }
    int lab[KNN];
#pragma unroll
    for (int u = 0; u < KNN; u++) lab[u] = targets[fi[u]];
    int bc = 0, bl = INT_MAX;
#pragma unroll
    for (int i = 0; i < KNN; i++) {
      int c = 0;
#pragma unroll
      for (int j = 0; j < KNN; j++) c += (lab[j] == lab[i]) ? 1 : 0;
      if (c > bc || (c == bc && lab[i] < bl)) { bc = c; bl = lab[i]; }
    }
    out[q] = (float)bl;
  }
}

extern "C" void kernel_launch(void* const* d_in, const int* in_sizes, int n_in,
                              void* d_out, int out_size, void* d_ws, size_t ws_size,
                              hipStream_t stream) {
  const float* Xm  = (const float*)d_in[0];
  const float* dat = (const float*)d_in[1];
  const int* targets = (const int*)d_in[2];
  float* out = (float*)d_out;
  float* ws  = (float*)d_ws;

  hipLaunchKernelGGL(convx_kernel, dim3(QN / 4), dim3(256), 0, stream, Xm, ws);
  hipLaunchKernelGGL(norms_kernel, dim3(NPAD / 4), dim3(256), 0, stream, dat, ws);
  hipLaunchKernelGGL(knn_chunk, dim3(QB, NS), dim3(256), 0, stream, dat, ws);
  hipLaunchKernelGGL(knn_final, dim3(QN), dim3(256), 0, stream, targets, ws, out);
}

// Round 5
// 420.182 us; speedup vs baseline: 2.8089x; 1.5535x over previous
//
#include <hip/hip_runtime.h>
#include <math.h>
#include <limits.h>

#define QN 1024
#define NN 50000
#define NPAD 50048
#define DD 512
#define KNN 10
#define NT 128            /* data points per block  */
#define QTB 128           /* queries per block      */
#define BK 32             /* k-chunk                */
#define NS 391            /* ceil(50000/128)        */
#define QB 8              /* 1024/128               */

/* workspace layout, in 4-byte words */
#define WS_D2 0
#define WS_XH NPAD                         /* X hi, bf16 row-major */
#define WS_XL (WS_XH + QN * DD / 2)
#define WS_CK (WS_XL + QN * DD / 2)        /* u64 keys: QN*NS*KNN (32 MB) */

typedef __attribute__((ext_vector_type(8))) short short8;  /* 8 bf16 = 4 VGPR */
typedef __attribute__((ext_vector_type(4))) float f32x4;
typedef unsigned long long u64;

/* order-preserving float -> u32, then pack with idx; plain u64 '<' ==
   lexicographic (dist, idx) ascending — matches top_k stability exactly */
__device__ __forceinline__ u64 mkkey(float f, int idx) {
  unsigned u = __float_as_uint(f);
  unsigned m = u ^ ((unsigned)((int)u >> 31) | 0x80000000u);
  return ((u64)m << 32) | (unsigned)idx;
}

/* split 2 floats into packed bf16 hi-pair and lo-pair words (RNE) */
__device__ __forceinline__ void cvt2(float x, float y, unsigned& hi, unsigned& lo) {
  unsigned ux = __float_as_uint(x), uy = __float_as_uint(y);
  unsigned rx = ux + 0x7fffu + ((ux >> 16) & 1u);
  unsigned ry = uy + 0x7fffu + ((uy >> 16) & 1u);
  hi = (rx >> 16) | (ry & 0xffff0000u);
  float xl = x - __uint_as_float(rx & 0xffff0000u);
  float yl = y - __uint_as_float(ry & 0xffff0000u);
  unsigned uxl = __float_as_uint(xl), uyl = __float_as_uint(yl);
  unsigned rxl = uxl + 0x7fffu + ((uxl >> 16) & 1u);
  unsigned ryl = uyl + 0x7fffu + ((uyl >> 16) & 1u);
  lo = (rxl >> 16) | (ryl & 0xffff0000u);
}

__device__ __forceinline__ void glds16(const void* g, void* l) {
  __builtin_amdgcn_global_load_lds(
      (const __attribute__((address_space(1))) unsigned*)g,
      (__attribute__((address_space(3))) unsigned*)l, 16, 0, 0);
}

/* branchless 10-slot sorted insert (ascending), u64 keys */
__device__ __forceinline__ void ins10(u64* kl, u64 k) {
#pragma unroll
  for (int u = 0; u < KNN; u++) {
    u64 lo = (k < kl[u]) ? k : kl[u];
    u64 hi = (k < kl[u]) ? kl[u] : k;
    kl[u] = lo; k = hi;
  }
}

/* ---------------- K0: preconvert X to split-bf16 row-major -------------- */
__global__ __launch_bounds__(256) void convx_kernel(
    const float* __restrict__ Xm, float* __restrict__ ws) {
  int w = threadIdx.x >> 6, lane = threadIdx.x & 63;
  int row = blockIdx.x * 4 + w;
  const float4* p = (const float4*)(Xm + (size_t)row * DD) + lane * 2;
  float4 v0 = p[0], v1 = p[1];
  unsigned h[4], l[4];
  cvt2(v0.x, v0.y, h[0], l[0]); cvt2(v0.z, v0.w, h[1], l[1]);
  cvt2(v1.x, v1.y, h[2], l[2]); cvt2(v1.z, v1.w, h[3], l[3]);
  ((uint4*)(ws + WS_XH))[row * 64 + lane] = make_uint4(h[0], h[1], h[2], h[3]);
  ((uint4*)(ws + WS_XL))[row * 64 + lane] = make_uint4(l[0], l[1], l[2], l[3]);
}

/* ---------------- K1: data row norms (padded with +inf) ---------------- */
__global__ __launch_bounds__(256) void norms_kernel(
    const float* __restrict__ dat, float* __restrict__ ws) {
  int w = threadIdx.x >> 6, lane = threadIdx.x & 63;
  int row = blockIdx.x * 4 + w;
  if (row >= NPAD) return;
  if (row >= NN) {
    if (lane == 0) ws[WS_D2 + row] = __builtin_inff();
    return;
  }
  const float4* p = (const float4*)(dat + (size_t)row * DD);
  float s = 0.f;
#pragma unroll
  for (int i = 0; i < 2; i++) {
    float4 v = p[lane + i * 64];
    s = fmaf(v.x, v.x, s); s = fmaf(v.y, v.y, s);
    s = fmaf(v.z, v.z, s); s = fmaf(v.w, v.w, s);
  }
#pragma unroll
  for (int off = 32; off; off >>= 1) s += __shfl_down(s, off, 64);
  if (lane == 0) ws[WS_D2 + row] = s;
}

/* ---------------- K2: split-bf16 MFMA GEMM + fused per-slice top-10 ----- */
struct StageT {
  unsigned char ah[8192], al[8192], bh[8192], bl[8192];  /* 8 panels x 1KB */
};
struct EpiT  { float sq[64][132]; };          /* 33.8 KB */
struct ListT { u64 kl[64][4][KNN]; };         /* 20.5 KB */
union SmemU { StageT s; EpiT e; ListT l; };

__global__ __launch_bounds__(256, 3) void knn_chunk(
    const float* __restrict__ dat, float* __restrict__ ws) {
  __shared__ __align__(16) SmemU sm;
  const int qbase = blockIdx.x * QTB;
  const int nbase = blockIdx.y * NT;
  const int t = threadIdx.x;
  const int lane = t & 63, wave = t >> 6;
  const int wn = wave & 1, wq = wave >> 1;
  const unsigned short* xh = (const unsigned short*)(ws + WS_XH);
  const unsigned short* xl = (const unsigned short*)(ws + WS_XL);

  f32x4 acc[4][4];
#pragma unroll
  for (int i = 0; i < 4; i++)
#pragma unroll
    for (int j = 0; j < 4; j++) acc[i][j] = (f32x4)0.f;

  /* B staging role: one thread = one row-half (16 k) */
  const int brow = t >> 1, bh_half = t & 1;
  const int bgr = nbase + brow;
  const int bpanel = (brow >> 4) * 1024;
  const int bchunk = (brow & 15) * 16;

  for (int kk = 0; kk < DD; kk += BK) {
    __syncthreads();
    /* ---- A staging: 16 panels (AH0..7, AL0..7), 4 per wave, pure DMA ---- */
#pragma unroll
    for (int i = 0; i < 4; i++) {
      int pp = wave * 4 + i;
      int p = pp & 7;
      const unsigned short* g =
          (pp < 8 ? xh : xl) +
          (size_t)(qbase + p * 16 + (lane & 15)) * DD + kk + (lane >> 4) * 8;
      unsigned char* ldst = (pp < 8 ? sm.s.ah : sm.s.al) + p * 1024;
      glds16(g, ldst);
    }
    /* ---- B staging: load 16 floats, split-convert, 4x ds_write_b128 ---- */
    {
      float4 v0 = make_float4(0.f, 0.f, 0.f, 0.f), v1 = v0, v2 = v0, v3 = v0;
      if (bgr < NN) {
        const float4* src = (const float4*)(dat + (size_t)bgr * DD + kk + bh_half * 16);
        v0 = src[0]; v1 = src[1]; v2 = src[2]; v3 = src[3];
      }
      unsigned hw[8], lw[8];
      cvt2(v0.x, v0.y, hw[0], lw[0]); cvt2(v0.z, v0.w, hw[1], lw[1]);
      cvt2(v1.x, v1.y, hw[2], lw[2]); cvt2(v1.z, v1.w, hw[3], lw[3]);
      cvt2(v2.x, v2.y, hw[4], lw[4]); cvt2(v2.z, v2.w, hw[5], lw[5]);
      cvt2(v3.x, v3.y, hw[6], lw[6]); cvt2(v3.z, v3.w, hw[7], lw[7]);
      unsigned char* bhp = sm.s.bh + bpanel;
      unsigned char* blp = sm.s.bl + bpanel;
      *(uint4*)(bhp + (2 * bh_half) * 256 + bchunk)     = make_uint4(hw[0], hw[1], hw[2], hw[3]);
      *(uint4*)(bhp + (2 * bh_half + 1) * 256 + bchunk) = make_uint4(hw[4], hw[5], hw[6], hw[7]);
      *(uint4*)(blp + (2 * bh_half) * 256 + bchunk)     = make_uint4(lw[0], lw[1], lw[2], lw[3]);
      *(uint4*)(blp + (2 * bh_half + 1) * 256 + bchunk) = make_uint4(lw[4], lw[5], lw[6], lw[7]);
    }
    __syncthreads();

    const int fragoff = lane * 16;
    short8 fah[4], fal[4], fbh[4], fbl[4];
#pragma unroll
    for (int i = 0; i < 4; i++) {
      fah[i] = *(const short8*)(sm.s.ah + (wq * 4 + i) * 1024 + fragoff);
      fal[i] = *(const short8*)(sm.s.al + (wq * 4 + i) * 1024 + fragoff);
      fbh[i] = *(const short8*)(sm.s.bh + (wn * 4 + i) * 1024 + fragoff);
      fbl[i] = *(const short8*)(sm.s.bl + (wn * 4 + i) * 1024 + fragoff);
    }
#pragma unroll
    for (int mt = 0; mt < 4; mt++)
#pragma unroll
      for (int nt = 0; nt < 4; nt++) {
        acc[mt][nt] = __builtin_amdgcn_mfma_f32_16x16x32_bf16(fah[mt], fbh[nt], acc[mt][nt], 0, 0, 0);
        acc[mt][nt] = __builtin_amdgcn_mfma_f32_16x16x32_bf16(fah[mt], fbl[nt], acc[mt][nt], 0, 0, 0);
        acc[mt][nt] = __builtin_amdgcn_mfma_f32_16x16x32_bf16(fal[mt], fbh[nt], acc[mt][nt], 0, 0, 0);
      }
  }

  /* ---- epilogue v2: 2 passes x 64 rows; u64 keys; branchless top-10.
     pass loop fully unrolled: runtime acc[] index -> scratch (R2 lesson). */
#pragma unroll
  for (int pass = 0; pass < 2; pass++) {
    __syncthreads();
    if (wq == pass) {                     /* dump sq = d2 - 2*dot */
#pragma unroll
      for (int nt = 0; nt < 4; nt++) {
        int col = wn * 64 + nt * 16 + (lane & 15);
        float d2v = ws[WS_D2 + nbase + col];
#pragma unroll
        for (int mt = 0; mt < 4; mt++)
#pragma unroll
          for (int rg = 0; rg < 4; rg++) {
            int lr = mt * 16 + (lane >> 4) * 4 + rg;
            sm.e.sq[lr][col] = fmaf(-2.f, acc[mt][nt][rg], d2v);
          }
      }
    }
    __syncthreads();
    /* selection: 4 threads/row, 32 cands each, bank-swizzled scan */
    {
      const int r = t >> 2, s = t & 3;
      u64 kl[KNN];
#pragma unroll
      for (int u = 0; u < KNN; u++) kl[u] = ~0ull;
      for (int jj = 0; jj < 32; jj++) {
        int c = s * 32 + ((jj + r + 8 * s) & 31);
        float v = sm.e.sq[r][c];
        ins10(kl, mkkey(v, nbase + c));
      }
      __syncthreads();                    /* sq consumed; reuse LDS */
#pragma unroll
      for (int u = 0; u < KNN; u++) sm.l.kl[r][s][u] = kl[u];
    }
    __syncthreads();
    if (t < 64) {                         /* 4-way merge, 1 thread/row */
      u64* dst = ((u64*)(ws + WS_CK)) +
                 ((size_t)(qbase + pass * 64 + t) * NS + blockIdx.y) * KNN;
      int h0 = 0, h1 = 0, h2 = 0, h3 = 0;
      for (int pick = 0; pick < KNN; pick++) {
        u64 k0 = sm.l.kl[t][0][h0], k1 = sm.l.kl[t][1][h1];
        u64 k2 = sm.l.kl[t][2][h2], k3 = sm.l.kl[t][3][h3];
        u64 best = k0; int bm = 0;
        if (k1 < best) { best = k1; bm = 1; }
        if (k2 < best) { best = k2; bm = 2; }
        if (k3 < best) { best = k3; bm = 3; }
        dst[pick] = best;
        h0 += (bm == 0); h1 += (bm == 1); h2 += (bm == 2); h3 += (bm == 3);
      }
    }
  }
}

/* ---------------- K3: per-query final merge + mode (u64 keys) ---------- */
__global__ __launch_bounds__(256) void knn_final(
    const int* __restrict__ targets, float* __restrict__ ws,
    float* __restrict__ out) {
  const int q = blockIdx.x;
  const int t = threadIdx.x;
  const u64* ck = ((const u64*)(ws + WS_CK)) + (size_t)q * NS * KNN;
  const int NC = NS * KNN;                 /* 3910 */

  u64 kl[KNN];
#pragma unroll
  for (int u = 0; u < KNN; u++) kl[u] = ~0ull;
  for (int j = t; j < NC; j += 256) ins10(kl, ck[j]);

  __shared__ u64 wk[256][KNN];
  __shared__ u64 m2[32][KNN];
  __shared__ u64 m3[4][KNN];
#pragma unroll
  for (int u = 0; u < KNN; u++) wk[t][u] = kl[u];
  __syncthreads();
  if (t < 32) {
    int h[8] = {0, 0, 0, 0, 0, 0, 0, 0};
    for (int pick = 0; pick < KNN; pick++) {
      u64 best = ~0ull; int bm = 0;
#pragma unroll
      for (int m = 0; m < 8; m++) {
        u64 km = wk[t * 8 + m][h[m]];
        if (km < best) { best = km; bm = m; }
      }
      m2[t][pick] = best;
#pragma unroll
      for (int m = 0; m < 8; m++) h[m] += (bm == m);
    }
  }
  __syncthreads();
  if (t < 4) {
    int h[8] = {0, 0, 0, 0, 0, 0, 0, 0};
    for (int pick = 0; pick < KNN; pick++) {
      u64 best = ~0ull; int bm = 0;
#pragma unroll
      for (int m = 0; m < 8; m++) {
        u64 km = m2[t * 8 + m][h[m]];
        if (km < best) { best = km; bm = m; }
      }
      m3[t][pick] = best;
#pragma unroll
      for (int m = 0; m < 8; m++) h[m] += (bm == m);
    }
  }
  __syncthreads();
  if (t == 0) {
    int h[4] = {0, 0, 0, 0};
    int fi[KNN];
    for (int pick = 0; pick < KNN; pick++) {
      u64 best = ~0ull; int bm = 0;
#pragma unroll
      for (int m = 0; m < 4; m++) {
        u64 km = m3[m][h[m]];
        if (km < best) { best = km; bm = m; }
      }
      fi[pick] = (int)(unsigned)(best & 0xffffffffu);
#pragma unroll
      for (int m = 0; m < 4; m++) h[m] += (bm == m);
    }
    int lab[KNN];
#pragma unroll
    for (int u = 0; u < KNN; u++) lab[u] = targets[fi[u]];
    int bc = 0, bl = INT_MAX;
#pragma unroll
    for (int i = 0; i < KNN; i++) {
      int c = 0;
#pragma unroll
      for (int j = 0; j < KNN; j++) c += (lab[j] == lab[i]) ? 1 : 0;
      if (c > bc || (c == bc && lab[i] < bl)) { bc = c; bl = lab[i]; }
    }
    out[q] = (float)bl;
  }
}

extern "C" void kernel_launch(void* const* d_in, const int* in_sizes, int n_in,
                              void* d_out, int out_size, void* d_ws, size_t ws_size,
                              hipStream_t stream) {
  const float* Xm  = (const float*)d_in[0];
  const float* dat = (const float*)d_in[1];
  const int* targets = (const int*)d_in[2];
  float* out = (float*)d_out;
  float* ws  = (float*)d_ws;

  hipLaunchKernelGGL(convx_kernel, dim3(QN / 4), dim3(256), 0, stream, Xm, ws);
  hipLaunchKernelGGL(norms_kernel, dim3(NPAD / 4), dim3(256), 0, stream, dat, ws);
  hipLaunchKernelGGL(knn_chunk, dim3(QB, NS), dim3(256), 0, stream, dat, ws);
  hipLaunchKernelGGL(knn_final, dim3(QN), dim3(256), 0, stream, targets, ws, out);
}

// Round 6
// 402.540 us; speedup vs baseline: 2.9320x; 1.0438x over previous
//
#include <hip/hip_runtime.h>
#include <math.h>
#include <limits.h>

#define QN 1024
#define NN 50000
#define NPAD 50048
#define DD 512
#define KNN 10
#define NT 128
#define QTB 128
#define BK 32
#define NS 391
#define QB 8
#define NSAMP 30          /* sampled slices for threshold */
#define NREST (NS - NSAMP)
#define CAP 512           /* per-query survivor buffer */

/* workspace layout, in 4-byte words */
#define WS_D2  0
#define WS_TAU 50048                       /* u64[1024] */
#define WS_CNT (WS_TAU + 2048)             /* u32[1024] */
#define WS_XH  (WS_CNT + 1024)             /* bf16 X hi row-major */
#define WS_XL  (WS_XH + QN * DD / 2)
#define WS_CKS (WS_XL + QN * DD / 2)       /* sampled keys u64[QN*NSAMP*KNN] */
#define WS_BUF (WS_CKS + QN * NSAMP * KNN * 2)  /* u64[QN*CAP] */
#define WS_DH  (WS_BUF + QN * CAP * 2)     /* tiled data hi: 391*16*8192 B */
#define WS_DL  (WS_DH + NS * 16 * 2048)
#define WS_END (WS_DL + NS * 16 * 2048)

typedef __attribute__((ext_vector_type(8))) short short8;
typedef __attribute__((ext_vector_type(4))) float f32x4;
typedef unsigned long long u64;

__device__ __forceinline__ u64 mkkey(float f, int idx) {
  unsigned u = __float_as_uint(f);
  unsigned m = u ^ ((unsigned)((int)u >> 31) | 0x80000000u);
  return ((u64)m << 32) | (unsigned)idx;
}

__device__ __forceinline__ void cvt2(float x, float y, unsigned& hi, unsigned& lo) {
  unsigned ux = __float_as_uint(x), uy = __float_as_uint(y);
  unsigned rx = ux + 0x7fffu + ((ux >> 16) & 1u);
  unsigned ry = uy + 0x7fffu + ((uy >> 16) & 1u);
  hi = (rx >> 16) | (ry & 0xffff0000u);
  float xl = x - __uint_as_float(rx & 0xffff0000u);
  float yl = y - __uint_as_float(ry & 0xffff0000u);
  unsigned uxl = __float_as_uint(xl), uyl = __float_as_uint(yl);
  unsigned rxl = uxl + 0x7fffu + ((uxl >> 16) & 1u);
  unsigned ryl = uyl + 0x7fffu + ((uyl >> 16) & 1u);
  lo = (rxl >> 16) | (ryl & 0xffff0000u);
}

__device__ __forceinline__ void glds16(const void* g, void* l) {
  __builtin_amdgcn_global_load_lds(
      (const __attribute__((address_space(1))) unsigned*)g,
      (__attribute__((address_space(3))) unsigned*)l, 16, 0, 0);
}

__device__ __forceinline__ void ins10(u64* kl, u64 k) {
#pragma unroll
  for (int u = 0; u < KNN; u++) {
    u64 lo = (k < kl[u]) ? k : kl[u];
    u64 hi = (k < kl[u]) ? kl[u] : k;
    kl[u] = lo; k = hi;
  }
}

/* ---------------- K0: preconvert X to split-bf16 row-major -------------- */
__global__ __launch_bounds__(256) void convx_kernel(
    const float* __restrict__ Xm, float* __restrict__ ws) {
  int w = threadIdx.x >> 6, lane = threadIdx.x & 63;
  int row = blockIdx.x * 4 + w;
  const float4* p = (const float4*)(Xm + (size_t)row * DD) + lane * 2;
  float4 v0 = p[0], v1 = p[1];
  unsigned h[4], l[4];
  cvt2(v0.x, v0.y, h[0], l[0]); cvt2(v0.z, v0.w, h[1], l[1]);
  cvt2(v1.x, v1.y, h[2], l[2]); cvt2(v1.z, v1.w, h[3], l[3]);
  ((uint4*)(ws + WS_XH))[row * 64 + lane] = make_uint4(h[0], h[1], h[2], h[3]);
  ((uint4*)(ws + WS_XL))[row * 64 + lane] = make_uint4(l[0], l[1], l[2], l[3]);
}

/* ---------------- K1: data row norms (padded with +inf) ---------------- */
__global__ __launch_bounds__(256) void norms_kernel(
    const float* __restrict__ dat, float* __restrict__ ws) {
  int w = threadIdx.x >> 6, lane = threadIdx.x & 63;
  int row = blockIdx.x * 4 + w;
  if (row >= NPAD) return;
  if (row >= NN) {
    if (lane == 0) ws[WS_D2 + row] = __builtin_inff();
    return;
  }
  const float4* p = (const float4*)(dat + (size_t)row * DD);
  float s = 0.f;
#pragma unroll
  for (int i = 0; i < 2; i++) {
    float4 v = p[lane + i * 64];
    s = fmaf(v.x, v.x, s); s = fmaf(v.y, v.y, s);
    s = fmaf(v.z, v.z, s); s = fmaf(v.w, v.w, s);
  }
#pragma unroll
  for (int off = 32; off; off >>= 1) s += __shfl_down(s, off, 64);
  if (lane == 0) ws[WS_D2 + row] = s;
}

/* ---------------- K1b: preconvert data to tiled split-bf16 LDS-image ---- */
__global__ __launch_bounds__(256) void convd_kernel(
    const float* __restrict__ dat, float* __restrict__ ws) {
  __shared__ __align__(16) unsigned char sbh[8192], sbl[8192];
  const int slice = blockIdx.x, kc = blockIdx.y;
  const int t = threadIdx.x;
  const int brow = t >> 1, half = t & 1;
  const int gr = slice * NT + brow;
  const int kk = kc * 32 + half * 16;
  float4 v0 = make_float4(0.f, 0.f, 0.f, 0.f), v1 = v0, v2 = v0, v3 = v0;
  if (gr < NN) {
    const float4* src = (const float4*)(dat + (size_t)gr * DD + kk);
    v0 = src[0]; v1 = src[1]; v2 = src[2]; v3 = src[3];
  }
  unsigned hw[8], lw[8];
  cvt2(v0.x, v0.y, hw[0], lw[0]); cvt2(v0.z, v0.w, hw[1], lw[1]);
  cvt2(v1.x, v1.y, hw[2], lw[2]); cvt2(v1.z, v1.w, hw[3], lw[3]);
  cvt2(v2.x, v2.y, hw[4], lw[4]); cvt2(v2.z, v2.w, hw[5], lw[5]);
  cvt2(v3.x, v3.y, hw[6], lw[6]); cvt2(v3.z, v3.w, hw[7], lw[7]);
  const int bpanel = (brow >> 4) * 1024, bchunk = (brow & 15) * 16;
  *(uint4*)(sbh + bpanel + (2 * half) * 256 + bchunk)     = make_uint4(hw[0], hw[1], hw[2], hw[3]);
  *(uint4*)(sbh + bpanel + (2 * half + 1) * 256 + bchunk) = make_uint4(hw[4], hw[5], hw[6], hw[7]);
  *(uint4*)(sbl + bpanel + (2 * half) * 256 + bchunk)     = make_uint4(lw[0], lw[1], lw[2], lw[3]);
  *(uint4*)(sbl + bpanel + (2 * half + 1) * 256 + bchunk) = make_uint4(lw[4], lw[5], lw[6], lw[7]);
  __syncthreads();
  uint4* dh = (uint4*)((unsigned char*)(ws + WS_DH) + ((size_t)slice * 16 + kc) * 8192);
  uint4* dl = (uint4*)((unsigned char*)(ws + WS_DL) + ((size_t)slice * 16 + kc) * 8192);
  dh[t] = ((uint4*)sbh)[t]; dh[t + 256] = ((uint4*)sbh)[t + 256];
  dl[t] = ((uint4*)sbl)[t]; dl[t + 256] = ((uint4*)sbl)[t + 256];
}

/* ---------------- K2: GEMM core; MODE 0 = full top-10 (sampled slices),
   MODE 1 = threshold filter; PRE 1 = B via preconverted tiles ------------ */
struct StageT { unsigned char ah[8192], al[8192], bh[8192], bl[8192]; };
struct EpiT  { float sq[64][132]; };
struct ListT { u64 kl[64][4][KNN]; };
union SmemU { StageT s; EpiT e; ListT l; u64 tau[128]; };

template <int PRE, int MODE>
__global__ __launch_bounds__(256, 3) void knn_chunk(
    const float* __restrict__ dat, float* __restrict__ ws, int soff) {
  __shared__ __align__(16) SmemU sm;
  const int qbase = blockIdx.x * QTB;
  const int slice = blockIdx.y + soff;
  const int nbase = slice * NT;
  const int t = threadIdx.x;
  const int lane = t & 63, wave = t >> 6;
  const int wn = wave & 1, wq = wave >> 1;
  const unsigned short* xh = (const unsigned short*)(ws + WS_XH);
  const unsigned short* xl = (const unsigned short*)(ws + WS_XL);
  const unsigned char* dh = (const unsigned char*)(ws + WS_DH);
  const unsigned char* dl = (const unsigned char*)(ws + WS_DL);

  f32x4 acc[4][4];
#pragma unroll
  for (int i = 0; i < 4; i++)
#pragma unroll
    for (int j = 0; j < 4; j++) acc[i][j] = (f32x4)0.f;

  const int brow = t >> 1, bh_half = t & 1;
  const int bgr = nbase + brow;
  const int bpanel = (brow >> 4) * 1024;
  const int bchunk = (brow & 15) * 16;

  for (int kk = 0; kk < DD; kk += BK) {
    __syncthreads();
    /* A staging: 16 panels, 4 glds16/wave */
#pragma unroll
    for (int i = 0; i < 4; i++) {
      int pp = wave * 4 + i;
      int p = pp & 7;
      const unsigned short* g =
          (pp < 8 ? xh : xl) +
          (size_t)(qbase + p * 16 + (lane & 15)) * DD + kk + (lane >> 4) * 8;
      unsigned char* ldst = (pp < 8 ? sm.s.ah : sm.s.al) + p * 1024;
      glds16(g, ldst);
    }
    if (PRE) {
      /* B staging: 16 panels from tiled DH/DL, contiguous 1KB, pure DMA */
      const int kc = kk >> 5;
#pragma unroll
      for (int i = 0; i < 4; i++) {
        int pp = wave * 4 + i;
        int p = pp & 7;
        const unsigned char* g = (pp < 8 ? dh : dl) +
            (((size_t)slice * 16 + kc) * 8 + p) * 1024 + lane * 16;
        unsigned char* ldst = (pp < 8 ? sm.s.bh : sm.s.bl) + p * 1024;
        glds16(g, ldst);
      }
    } else {
      float4 v0 = make_float4(0.f, 0.f, 0.f, 0.f), v1 = v0, v2 = v0, v3 = v0;
      if (bgr < NN) {
        const float4* src = (const float4*)(dat + (size_t)bgr * DD + kk + bh_half * 16);
        v0 = src[0]; v1 = src[1]; v2 = src[2]; v3 = src[3];
      }
      unsigned hw[8], lw[8];
      cvt2(v0.x, v0.y, hw[0], lw[0]); cvt2(v0.z, v0.w, hw[1], lw[1]);
      cvt2(v1.x, v1.y, hw[2], lw[2]); cvt2(v1.z, v1.w, hw[3], lw[3]);
      cvt2(v2.x, v2.y, hw[4], lw[4]); cvt2(v2.z, v2.w, hw[5], lw[5]);
      cvt2(v3.x, v3.y, hw[6], lw[6]); cvt2(v3.z, v3.w, hw[7], lw[7]);
      unsigned char* bhp = sm.s.bh + bpanel;
      unsigned char* blp = sm.s.bl + bpanel;
      *(uint4*)(bhp + (2 * bh_half) * 256 + bchunk)     = make_uint4(hw[0], hw[1], hw[2], hw[3]);
      *(uint4*)(bhp + (2 * bh_half + 1) * 256 + bchunk) = make_uint4(hw[4], hw[5], hw[6], hw[7]);
      *(uint4*)(blp + (2 * bh_half) * 256 + bchunk)     = make_uint4(lw[0], lw[1], lw[2], lw[3]);
      *(uint4*)(blp + (2 * bh_half + 1) * 256 + bchunk) = make_uint4(lw[4], lw[5], lw[6], lw[7]);
    }
    __syncthreads();

    const int fragoff = lane * 16;
    short8 fah[4], fal[4], fbh[4], fbl[4];
#pragma unroll
    for (int i = 0; i < 4; i++) {
      fah[i] = *(const short8*)(sm.s.ah + (wq * 4 + i) * 1024 + fragoff);
      fal[i] = *(const short8*)(sm.s.al + (wq * 4 + i) * 1024 + fragoff);
      fbh[i] = *(const short8*)(sm.s.bh + (wn * 4 + i) * 1024 + fragoff);
      fbl[i] = *(const short8*)(sm.s.bl + (wn * 4 + i) * 1024 + fragoff);
    }
#pragma unroll
    for (int mt = 0; mt < 4; mt++)
#pragma unroll
      for (int nt = 0; nt < 4; nt++) {
        acc[mt][nt] = __builtin_amdgcn_mfma_f32_16x16x32_bf16(fah[mt], fbh[nt], acc[mt][nt], 0, 0, 0);
        acc[mt][nt] = __builtin_amdgcn_mfma_f32_16x16x32_bf16(fah[mt], fbl[nt], acc[mt][nt], 0, 0, 0);
        acc[mt][nt] = __builtin_amdgcn_mfma_f32_16x16x32_bf16(fal[mt], fbh[nt], acc[mt][nt], 0, 0, 0);
      }
  }

  if (MODE == 0) {
    /* full per-slice top-10 (sampled slices) -> WS_CKS, stride NSAMP */
#pragma unroll
    for (int pass = 0; pass < 2; pass++) {
      __syncthreads();
      if (wq == pass) {
#pragma unroll
        for (int nt = 0; nt < 4; nt++) {
          int col = wn * 64 + nt * 16 + (lane & 15);
          float d2v = ws[WS_D2 + nbase + col];
#pragma unroll
          for (int mt = 0; mt < 4; mt++)
#pragma unroll
            for (int rg = 0; rg < 4; rg++) {
              int lr = mt * 16 + (lane >> 4) * 4 + rg;
              sm.e.sq[lr][col] = fmaf(-2.f, acc[mt][nt][rg], d2v);
            }
        }
      }
      __syncthreads();
      {
        const int r = t >> 2, s = t & 3;
        u64 kl[KNN];
#pragma unroll
        for (int u = 0; u < KNN; u++) kl[u] = ~0ull;
        for (int jj = 0; jj < 32; jj++) {
          int c = s * 32 + ((jj + r + 8 * s) & 31);
          float v = sm.e.sq[r][c];
          ins10(kl, mkkey(v, nbase + c));
        }
        __syncthreads();
#pragma unroll
        for (int u = 0; u < KNN; u++) sm.l.kl[r][s][u] = kl[u];
      }
      __syncthreads();
      if (t < 64) {
        u64* dst = ((u64*)(ws + WS_CKS)) +
                   ((size_t)(qbase + pass * 64 + t) * NSAMP + blockIdx.y) * KNN;
        int h0 = 0, h1 = 0, h2 = 0, h3 = 0;
        for (int pick = 0; pick < KNN; pick++) {
          u64 k0 = sm.l.kl[t][0][h0], k1 = sm.l.kl[t][1][h1];
          u64 k2 = sm.l.kl[t][2][h2], k3 = sm.l.kl[t][3][h3];
          u64 best = k0; int bm = 0;
          if (k1 < best) { best = k1; bm = 1; }
          if (k2 < best) { best = k2; bm = 2; }
          if (k3 < best) { best = k3; bm = 3; }
          dst[pick] = best;
          h0 += (bm == 0); h1 += (bm == 1); h2 += (bm == 2); h3 += (bm == 3);
        }
      }
    }
  } else {
    /* threshold filter: append keys < tau[row] to per-query buffer */
    __syncthreads();
    if (t < 128) sm.tau[t] = ((const u64*)(ws + WS_TAU))[qbase + t];
    __syncthreads();
    unsigned* cnt = (unsigned*)(ws + WS_CNT);
    u64* buf = (u64*)(ws + WS_BUF);
    float d2v[4];
#pragma unroll
    for (int nt = 0; nt < 4; nt++)
      d2v[nt] = ws[WS_D2 + nbase + wn * 64 + nt * 16 + (lane & 15)];
#pragma unroll
    for (int mt = 0; mt < 4; mt++)
#pragma unroll
      for (int rg = 0; rg < 4; rg++) {
        int row = wq * 64 + mt * 16 + (lane >> 4) * 4 + rg;
        u64 tr = sm.tau[row];
#pragma unroll
        for (int nt = 0; nt < 4; nt++) {
          float d = fmaf(-2.f, acc[mt][nt][rg], d2v[nt]);
          int col = nbase + wn * 64 + nt * 16 + (lane & 15);
          u64 key = mkkey(d, col);
          if (key < tr) {
            int q = qbase + row;
            unsigned slot = atomicAdd(cnt + q, 1u);
            if (slot < CAP) buf[(size_t)q * CAP + slot] = key;
          }
        }
      }
  }
}

/* ---------------- K2t: per-query tau = 10th of sampled keys ------------ */
__global__ __launch_bounds__(64) void tau_kernel(float* __restrict__ ws) {
  const int q = blockIdx.x;
  const int t = threadIdx.x;
  const u64* samp = ((const u64*)(ws + WS_CKS)) + (size_t)q * NSAMP * KNN;
  const int NC = NSAMP * KNN;              /* 300 */
  u64 kl[KNN];
#pragma unroll
  for (int u = 0; u < KNN; u++) kl[u] = ~0ull;
  for (int j = t; j < NC; j += 64) ins10(kl, samp[j]);
  __shared__ u64 wk[64][KNN];
  __shared__ u64 m2[8][KNN];
#pragma unroll
  for (int u = 0; u < KNN; u++) wk[t][u] = kl[u];
  __syncthreads();
  if (t < 8) {
    int h[8] = {0, 0, 0, 0, 0, 0, 0, 0};
    for (int pick = 0; pick < KNN; pick++) {
      u64 best = ~0ull; int bm = 0;
#pragma unroll
      for (int m = 0; m < 8; m++) {
        u64 km = wk[t * 8 + m][h[m]];
        if (km < best) { best = km; bm = m; }
      }
      m2[t][pick] = best;
#pragma unroll
      for (int m = 0; m < 8; m++) h[m] += (bm == m);
    }
  }
  __syncthreads();
  if (t == 0) {
    int h[8] = {0, 0, 0, 0, 0, 0, 0, 0};
    u64 best = 0;
    for (int pick = 0; pick < KNN; pick++) {
      best = ~0ull; int bm = 0;
#pragma unroll
      for (int m = 0; m < 8; m++) {
        u64 km = m2[m][h[m]];
        if (km < best) { best = km; bm = m; }
      }
#pragma unroll
      for (int m = 0; m < 8; m++) h[m] += (bm == m);
    }
    ((u64*)(ws + WS_TAU))[q] = best;       /* 10th smallest sampled key */
    ((unsigned*)(ws + WS_CNT))[q] = 0u;
  }
}

/* ---------------- K3: final top-10 (sampled + survivors) + mode -------- */
__global__ __launch_bounds__(64) void knn_final(
    const int* __restrict__ targets, float* __restrict__ ws,
    float* __restrict__ out) {
  const int q = blockIdx.x;
  const int t = threadIdx.x;
  const u64* samp = ((const u64*)(ws + WS_CKS)) + (size_t)q * NSAMP * KNN;
  const u64* buf = ((const u64*)(ws + WS_BUF)) + (size_t)q * CAP;
  unsigned c = ((const unsigned*)(ws + WS_CNT))[q];
  if (c > CAP) c = CAP;

  u64 kl[KNN];
#pragma unroll
  for (int u = 0; u < KNN; u++) kl[u] = ~0ull;
  for (int j = t; j < NSAMP * KNN; j += 64) ins10(kl, samp[j]);
  for (int j = t; j < (int)c; j += 64) ins10(kl, buf[j]);

  __shared__ u64 wk[64][KNN];
  __shared__ u64 m2[8][KNN];
#pragma unroll
  for (int u = 0; u < KNN; u++) wk[t][u] = kl[u];
  __syncthreads();
  if (t < 8) {
    int h[8] = {0, 0, 0, 0, 0, 0, 0, 0};
    for (int pick = 0; pick < KNN; pick++) {
      u64 best = ~0ull; int bm = 0;
#pragma unroll
      for (int m = 0; m < 8; m++) {
        u64 km = wk[t * 8 + m][h[m]];
        if (km < best) { best = km; bm = m; }
      }
      m2[t][pick] = best;
#pragma unroll
      for (int m = 0; m < 8; m++) h[m] += (bm == m);
    }
  }
  __syncthreads();
  if (t == 0) {
    int h[8] = {0, 0, 0, 0, 0, 0, 0, 0};
    int fi[KNN];
    for (int pick = 0; pick < KNN; pick++) {
      u64 best = ~0ull; int bm = 0;
#pragma unroll
      for (int m = 0; m < 8; m++) {
        u64 km = m2[m][h[m]];
        if (km < best) { best = km; bm = m; }
      }
      fi[pick] = (int)(unsigned)(best & 0xffffffffu);
#pragma unroll
      for (int m = 0; m < 8; m++) h[m] += (bm == m);
    }
    int lab[KNN];
#pragma unroll
    for (int u = 0; u < KNN; u++) lab[u] = targets[fi[u]];
    int bc = 0, bl = INT_MAX;
#pragma unroll
    for (int i = 0; i < KNN; i++) {
      int cc = 0;
#pragma unroll
      for (int j = 0; j < KNN; j++) cc += (lab[j] == lab[i]) ? 1 : 0;
      if (cc > bc || (cc == bc && lab[i] < bl)) { bc = cc; bl = lab[i]; }
    }
    out[q] = (float)bl;
  }
}

extern "C" void kernel_launch(void* const* d_in, const int* in_sizes, int n_in,
                              void* d_out, int out_size, void* d_ws, size_t ws_size,
                              hipStream_t stream) {
  const float* Xm  = (const float*)d_in[0];
  const float* dat = (const float*)d_in[1];
  const int* targets = (const int*)d_in[2];
  float* out = (float*)d_out;
  float* ws  = (float*)d_ws;
  const bool pre = ws_size >= (size_t)WS_END * 4;   /* constant per process */

  hipLaunchKernelGGL(convx_kernel, dim3(QN / 4), dim3(256), 0, stream, Xm, ws);
  hipLaunchKernelGGL(norms_kernel, dim3(NPAD / 4), dim3(256), 0, stream, dat, ws);
  if (pre) {
    hipLaunchKernelGGL(convd_kernel, dim3(NS, 16), dim3(256), 0, stream, dat, ws);
    hipLaunchKernelGGL((knn_chunk<1, 0>), dim3(QB, NSAMP), dim3(256), 0, stream, dat, ws, 0);
    hipLaunchKernelGGL(tau_kernel, dim3(QN), dim3(64), 0, stream, ws);
    hipLaunchKernelGGL((knn_chunk<1, 1>), dim3(QB, NREST), dim3(256), 0, stream, dat, ws, NSAMP);
  } else {
    hipLaunchKernelGGL((knn_chunk<0, 0>), dim3(QB, NSAMP), dim3(256), 0, stream, dat, ws, 0);
    hipLaunchKernelGGL(tau_kernel, dim3(QN), dim3(64), 0, stream, ws);
    hipLaunchKernelGGL((knn_chunk<0, 1>), dim3(QB, NREST), dim3(256), 0, stream, dat, ws, NSAMP);
  }
  hipLaunchKernelGGL(knn_final, dim3(QN), dim3(64), 0, stream, targets, ws, out);
}